// Round 3
// baseline (195.440 us; speedup 1.0000x reference)
//
#include <hip/hip_runtime.h>
#include <hip/hip_bf16.h>

typedef __attribute__((ext_vector_type(4))) float f32x4;
typedef __attribute__((ext_vector_type(2))) float f32x2;
typedef __attribute__((ext_vector_type(8))) short s16x8;
typedef __attribute__((ext_vector_type(4))) unsigned short u16x4;
typedef __attribute__((ext_vector_type(8))) __bf16 bf16x8;

#define HDIM 512
#define SEQ  2048
#define NB   64
#define BM   64
#define CCH  16

// round-to-nearest-even fp32 -> bf16 bits
static __device__ __forceinline__ unsigned short f2bf(float f) {
  unsigned u = __float_as_uint(f);
  u += 0x7fffu + ((u >> 16) & 1u);
  return (unsigned short)(u >> 16);
}

static __device__ __forceinline__ f32x4 mfma16(s16x8 a, s16x8 b, f32x4 c) {
  return __builtin_amdgcn_mfma_f32_16x16x32_bf16(
      __builtin_bit_cast(bf16x8, a), __builtin_bit_cast(bf16x8, b), c, 0, 0, 0);
}

// ---------------- kernel 0a: W1 fp32 -> bf16, k-step-major -------------------
// 16B chunk id = kk*2048 + n*4 + r4 holds W1[n][kk*32 + r4*8 .. +8] as bf16.
// gemm B-frag read (one nf, 64 lanes) then covers a CONTIGUOUS 1 KiB segment.
__global__ void convert_w1(const float* __restrict__ w1,
                           unsigned short* __restrict__ o) {
  int id = blockIdx.x * 256 + threadIdx.x;   // 32768 chunks of 16B
  int kk = id >> 11, n = (id >> 2) & 511, r4 = id & 3;
  const float* src = w1 + (long)n * HDIM + kk * 32 + r4 * 8;
  f32x4 v0 = *(const f32x4*)src;
  f32x4 v1 = *(const f32x4*)(src + 4);
  u16x4 a, b;
  a.x = f2bf(v0.x); a.y = f2bf(v0.y); a.z = f2bf(v0.z); a.w = f2bf(v0.w);
  b.x = f2bf(v1.x); b.y = f2bf(v1.y); b.z = f2bf(v1.z); b.w = f2bf(v1.w);
  unsigned short* dst = o + (long)id * 8;
  *(u16x4*)dst = a;
  *(u16x4*)(dst + 4) = b;
}

// ---------------- kernel 0b: z[b][o] = dec[b]·W2[o] + b2[o] + b1[o] ----------
__global__ void zproj(const float* __restrict__ dec, const float* __restrict__ W2,
                      const float* __restrict__ b1, const float* __restrict__ b2,
                      float* __restrict__ zfull) {
  int b = blockIdx.x, oc = blockIdx.y, tid = threadIdx.x;
  int o = oc * 256 + tid;
  __shared__ float d_s[HDIM];
  d_s[tid] = dec[b * HDIM + tid];
  d_s[tid + 256] = dec[b * HDIM + tid + 256];
  __syncthreads();
  const float* w = W2 + (long)o * HDIM;
  float s = 0.f;
#pragma unroll 4
  for (int k = 0; k < HDIM; k += 4) {
    f32x4 v = *(const f32x4*)(w + k);
    s += v.x * d_s[k] + v.y * d_s[k + 1] + v.z * d_s[k + 2] + v.w * d_s[k + 3];
  }
  zfull[b * HDIM + o] = s + b1[o] + b2[o];
}

// ---------------- kernel 1: fused GEMM + tanh + V-dot -> scores --------------
// A (64 x 512) staged ONCE in LDS (bf16, XOR-swizzled); B read per-fragment
// straight from L2-resident w1k. Barrier-free fully-unrolled K-loop.
__global__ __launch_bounds__(512, 4)
void gemm_scores(const float* __restrict__ enc, const unsigned short* __restrict__ w1k,
                 const float* __restrict__ zfull, const float* __restrict__ V,
                 const float* __restrict__ bv, float* __restrict__ scores) {
  __shared__ unsigned short Asm[BM * HDIM];       // 64 KiB
  __shared__ float zbuf[HDIM];                    // 2 KiB
  __shared__ float vbuf[HDIM];                    // 2 KiB
  __shared__ float red[8][BM];                    // 2 KiB   -> 70 KiB, 2 blk/CU

  const int tid = threadIdx.x;
  const int wid = tid >> 6;
  const int lane = tid & 63;
  const long m0 = (long)blockIdx.x * BM;
  const int b = (int)(m0 >> 11);

  zbuf[tid] = zfull[b * HDIM + tid];
  vbuf[tid] = V[tid];

  // ---- phase 0: stage A tile (fp32 -> bf16, swizzled) ----
  // global fp32 16B chunk g = j*512 + tid  (perfectly coalesced 8 KiB/instr)
  // row = g>>7, qf32 = g&127 (const per thread); bf16 chunk q = qf32>>1,
  // phys p = q ^ (row&7); write 8B at row*1024 + p*16 + (qf32&1)*8.
  {
    const float* Ablk = enc + m0 * HDIM;
    const int qf32 = tid & 127;
    const int rbase = tid >> 7;
    const int q = qf32 >> 1, half = qf32 & 1;
#pragma unroll
    for (int j = 0; j < 16; ++j) {
      const int row = j * 4 + rbase;
      f32x4 v = *(const f32x4*)(Ablk + (long)row * HDIM + qf32 * 4);
      u16x4 pk;
      pk.x = f2bf(v.x); pk.y = f2bf(v.y); pk.z = f2bf(v.z); pk.w = f2bf(v.w);
      *(u16x4*)((char*)Asm + row * 1024 + ((q ^ (row & 7)) * 16) + half * 8) = pk;
    }
  }
  __syncthreads();

  // ---- K-loop: no barriers, no LDS writes ----
  const int r4 = lane >> 4, c15 = lane & 15, c7 = c15 & 7;
  // A phys chunk p = (kk*4 + r4) ^ c7 -> byte = (kk>>1)*128 + ((kk&1)^kb)*64 + rs*16
  const int rs = r4 ^ (c7 & 3), kb = c7 >> 2;
  const char* Ab = (const char*)Asm;
  const int a0 = c15 * 1024 + rs * 16 + kb * 64;        // even kk
  const int a1 = c15 * 1024 + rs * 16 + (kb ^ 1) * 64;  // odd  kk
  // B: ushort addr = kk*16384 + n*32 + r4*8, n = wid*64 + nf*16 + c15
  const unsigned short* bp = w1k + (wid * 64 + c15) * 32 + r4 * 8;

  f32x4 acc[4][4] = {};

#pragma unroll
  for (int kk = 0; kk < 16; ++kk) {
    s16x8 af[4], bfr[4];
    const int ab = ((kk & 1) ? a1 : a0) + (kk >> 1) * 128;
#pragma unroll
    for (int nf = 0; nf < 4; ++nf)
      bfr[nf] = *(const s16x8*)(bp + kk * 16384 + nf * 512);
#pragma unroll
    for (int mf = 0; mf < 4; ++mf)
      af[mf] = *(const s16x8*)(Ab + ab + mf * 16384);
#pragma unroll
    for (int mf = 0; mf < 4; ++mf)
#pragma unroll
      for (int nf = 0; nf < 4; ++nf)
        acc[mf][nf] = mfma16(af[mf], bfr[nf], acc[mf][nf]);
  }

  // ---- epilogue: scores[m] = sum_n tanh(acc + z[n]) * V[n] + bv ----
  // C/D layout (16x16x32): col = lane&15, row = (lane>>4)*4 + j   [m89/m91]
#pragma unroll
  for (int mf = 0; mf < 4; ++mf) {
#pragma unroll
    for (int j = 0; j < 4; ++j) {
      float s = 0.f;
#pragma unroll
      for (int nf = 0; nf < 4; ++nf) {
        const int n = wid * 64 + nf * 16 + c15;
        float x = acc[mf][nf][j] + zbuf[n];
        float e = __expf(2.f * x);
        float t = 1.f - 2.f * __builtin_amdgcn_rcpf(e + 1.f);  // tanh(x)
        s += t * vbuf[n];
      }
      s += __shfl_xor(s, 1); s += __shfl_xor(s, 2);
      s += __shfl_xor(s, 4); s += __shfl_xor(s, 8);
      if (c15 == 0) red[wid][mf * 16 + r4 * 4 + j] = s;
    }
  }
  __syncthreads();
  if (tid < BM) {
    float s = 0.f;
#pragma unroll
    for (int w = 0; w < 8; ++w) s += red[w][tid];
    scores[m0 + tid] = s + bv[0];
  }
}

// ---------------- kernel 2: per-batch softmax over S=2048 (in place) ---------
__global__ void softmax_k(const float* __restrict__ scores, float* __restrict__ attn) {
  int b = blockIdx.x, tid = threadIdx.x;
  const float* s = scores + (long)b * SEQ;
  float v[8];
  float mx = -1e30f;
#pragma unroll
  for (int i = 0; i < 8; ++i) { v[i] = s[i * 256 + tid]; mx = fmaxf(mx, v[i]); }
  for (int off = 1; off < 64; off <<= 1) mx = fmaxf(mx, __shfl_xor(mx, off));
  __shared__ float redm[4];
  __shared__ float redz[4];
  int w = tid >> 6, ln = tid & 63;
  if (ln == 0) redm[w] = mx;
  __syncthreads();
  mx = fmaxf(fmaxf(redm[0], redm[1]), fmaxf(redm[2], redm[3]));
  float z = 0.f;
#pragma unroll
  for (int i = 0; i < 8; ++i) { v[i] = __expf(v[i] - mx); z += v[i]; }
  for (int off = 1; off < 64; off <<= 1) z += __shfl_xor(z, off);
  if (ln == 0) redz[w] = z;
  __syncthreads();
  z = redz[0] + redz[1] + redz[2] + redz[3];
  float inv = 1.f / z;
#pragma unroll
  for (int i = 0; i < 8; ++i) attn[(long)b * SEQ + i * 256 + tid] = v[i] * inv;
}

// ---------------- kernel 3: partial context over s-chunks --------------------
__global__ void ctx_partial(const float* __restrict__ enc, const float* __restrict__ attn,
                            float* __restrict__ partial) {
  int b = blockIdx.x, c = blockIdx.y, tid = threadIdx.x;
  __shared__ float a_s[SEQ / CCH];
  if (tid < SEQ / CCH) a_s[tid] = attn[(long)b * SEQ + c * (SEQ / CCH) + tid];
  __syncthreads();
  const float* e = enc + ((long)b * SEQ + (long)c * (SEQ / CCH)) * HDIM + tid * 2;
  float ax = 0.f, ay = 0.f;
#pragma unroll 4
  for (int s = 0; s < SEQ / CCH; ++s) {
    f32x2 v = *(const f32x2*)(e + (long)s * HDIM);
    float a = a_s[s];
    ax += a * v.x; ay += a * v.y;
  }
  f32x2 r; r.x = ax; r.y = ay;
  *(f32x2*)(partial + ((long)(b * CCH + c) * HDIM) + tid * 2) = r;
}

// ---------------- kernel 4: reduce partials -> context -----------------------
__global__ void ctx_reduce(const float* __restrict__ partial, float* __restrict__ ctx) {
  int i = blockIdx.x * 256 + threadIdx.x;   // 32768 = 64*512
  int b = i >> 9, h = i & 511;
  const float* p = partial + (long)b * CCH * HDIM + h;
  float s = 0.f;
#pragma unroll
  for (int c = 0; c < CCH; ++c) s += p[c * HDIM];
  ctx[i] = s;
}

extern "C" void kernel_launch(void* const* d_in, const int* in_sizes, int n_in,
                              void* d_out, int out_size, void* d_ws, size_t ws_size,
                              hipStream_t stream) {
  const float* enc = (const float*)d_in[0];
  const float* dec = (const float*)d_in[1];
  const float* W1  = (const float*)d_in[2];
  const float* b1  = (const float*)d_in[3];
  const float* W2  = (const float*)d_in[4];
  const float* b2  = (const float*)d_in[5];
  const float* V   = (const float*)d_in[6];
  const float* bv  = (const float*)d_in[7];

  float* out  = (float*)d_out;
  float* ctx  = out;                       // 64*512
  float* attn = out + NB * HDIM;           // 64*2048 (raw scores first, softmaxed in place)

  char* ws = (char*)d_ws;
  unsigned short* w1k = (unsigned short*)ws;                 // 512 KiB (k-step-major)
  float* zfull   = (float*)(ws + 524288);                    // 128 KiB
  float* partial = (float*)(ws + 524288 + 131072);           // 2 MiB
  (void)in_sizes; (void)n_in; (void)out_size; (void)ws_size;

  convert_w1<<<128, 256, 0, stream>>>(W1, w1k);
  zproj<<<dim3(NB, 2), 256, 0, stream>>>(dec, W2, b1, b2, zfull);
  gemm_scores<<<(NB * SEQ) / BM, 512, 0, stream>>>(enc, w1k, zfull, V, bv, attn);
  softmax_k<<<NB, 256, 0, stream>>>(attn, attn);
  ctx_partial<<<dim3(NB, CCH), 256, 0, stream>>>(enc, attn, partial);
  ctx_reduce<<<128, 256, 0, stream>>>(partial, ctx);
}

// Round 4
// 157.454 us; speedup vs baseline: 1.2412x; 1.2412x over previous
//
#include <hip/hip_runtime.h>
#include <hip/hip_bf16.h>

typedef __attribute__((ext_vector_type(4))) float f32x4;
typedef __attribute__((ext_vector_type(8))) short s16x8;
typedef __attribute__((ext_vector_type(4))) unsigned short u16x4;
typedef __attribute__((ext_vector_type(8))) __bf16 bf16x8;

#define HDIM 512
#define SEQ  2048
#define NB   64
#define BM   64
#define NBLK ((NB * SEQ) / BM)   // 2048 blocks
#define CPB  (SEQ / BM)          // 32 chunks per batch

// round-to-nearest-even fp32 -> bf16 bits
static __device__ __forceinline__ unsigned short f2bf(float f) {
  unsigned u = __float_as_uint(f);
  u += 0x7fffu + ((u >> 16) & 1u);
  return (unsigned short)(u >> 16);
}
static __device__ __forceinline__ float bf2f(unsigned short v) {
  return __uint_as_float(((unsigned)v) << 16);
}

static __device__ __forceinline__ f32x4 mfma16(s16x8 a, s16x8 b, f32x4 c) {
  return __builtin_amdgcn_mfma_f32_16x16x32_bf16(
      __builtin_bit_cast(bf16x8, a), __builtin_bit_cast(bf16x8, b), c, 0, 0, 0);
}

// ---------------- kernel 0a: W1 fp32 -> bf16, k-step-major -------------------
// 16B chunk id = kk*2048 + n*4 + r4 holds W1[n][kk*32 + r4*8 .. +8] as bf16.
__global__ void convert_w1(const float* __restrict__ w1,
                           unsigned short* __restrict__ o) {
  int id = blockIdx.x * 256 + threadIdx.x;   // 32768 chunks of 16B
  int kk = id >> 11, n = (id >> 2) & 511, r4 = id & 3;
  const float* src = w1 + (long)n * HDIM + kk * 32 + r4 * 8;
  f32x4 v0 = *(const f32x4*)src;
  f32x4 v1 = *(const f32x4*)(src + 4);
  u16x4 a, b;
  a.x = f2bf(v0.x); a.y = f2bf(v0.y); a.z = f2bf(v0.z); a.w = f2bf(v0.w);
  b.x = f2bf(v1.x); b.y = f2bf(v1.y); b.z = f2bf(v1.z); b.w = f2bf(v1.w);
  unsigned short* dst = o + (long)id * 8;
  *(u16x4*)dst = a;
  *(u16x4*)(dst + 4) = b;
}

// ---------------- kernel 0b: z[b][o] = dec[b]·W2[o] + b2[o] + b1[o] ----------
__global__ void zproj(const float* __restrict__ dec, const float* __restrict__ W2,
                      const float* __restrict__ b1, const float* __restrict__ b2,
                      float* __restrict__ zfull) {
  int b = blockIdx.x, oc = blockIdx.y, tid = threadIdx.x;
  int o = oc * 256 + tid;
  __shared__ float d_s[HDIM];
  d_s[tid] = dec[b * HDIM + tid];
  d_s[tid + 256] = dec[b * HDIM + tid + 256];
  __syncthreads();
  const float* w = W2 + (long)o * HDIM;
  float s = 0.f;
#pragma unroll 4
  for (int k = 0; k < HDIM; k += 4) {
    f32x4 v = *(const f32x4*)(w + k);
    s += v.x * d_s[k] + v.y * d_s[k + 1] + v.z * d_s[k + 2] + v.w * d_s[k + 3];
  }
  zfull[b * HDIM + o] = s + b1[o] + b2[o];
}

// ------ kernel 1: fused GEMM + tanh + V-dot + local softmax + partial ctx ----
// Per block (64 rows): scores (raw) -> attn buf; (m_c,l_c) -> ml; partial
// context from the LDS-resident A tile -> pctx (bf16).
__global__ __launch_bounds__(512, 4)
void gemm_fused(const float* __restrict__ enc, const unsigned short* __restrict__ w1k,
                const float* __restrict__ zfull, const float* __restrict__ V,
                const float* __restrict__ bv, float* __restrict__ scores,
                unsigned short* __restrict__ pctx, float* __restrict__ ml) {
  __shared__ __align__(16) char pool[71936];
  unsigned short* Asm = (unsigned short*)pool;            // 64 KiB bf16 tile
  float* zbuf = (float*)(pool + 65536);                   // 512 f
  float* vbuf = (float*)(pool + 67584);                   // 512 f
  float* red  = (float*)(pool + 69632);                   // 8*64 f
  float* plds = (float*)(pool + 71680);                   // 64 f

  const int tid = threadIdx.x;
  const int wid = tid >> 6;
  const int lane = tid & 63;
  const long m0 = (long)blockIdx.x * BM;
  const int b = (int)(m0 >> 11);

  zbuf[tid] = zfull[b * HDIM + tid];
  vbuf[tid] = V[tid];

  // ---- phase 0: stage A tile (fp32 -> bf16, XOR-swizzled) ----
  {
    const float* Ablk = enc + m0 * HDIM;
    const int qf32 = tid & 127;
    const int rbase = tid >> 7;
    const int q = qf32 >> 1, half = qf32 & 1;
#pragma unroll
    for (int j = 0; j < 16; ++j) {
      const int row = j * 4 + rbase;
      f32x4 v = *(const f32x4*)(Ablk + (long)row * HDIM + qf32 * 4);
      u16x4 pk;
      pk.x = f2bf(v.x); pk.y = f2bf(v.y); pk.z = f2bf(v.z); pk.w = f2bf(v.w);
      *(u16x4*)((char*)Asm + row * 1024 + ((q ^ (row & 7)) * 16) + half * 8) = pk;
    }
  }

  const int r4 = lane >> 4, c15 = lane & 15, c7 = c15 & 7;
  const int rs = r4 ^ (c7 & 3), kb = c7 >> 2;
  const char* Ab = (const char*)Asm;
  const int a0 = c15 * 1024 + rs * 16 + kb * 64;        // even kk
  const int a1 = c15 * 1024 + rs * 16 + (kb ^ 1) * 64;  // odd  kk
  const unsigned short* bp = w1k + (wid * 64 + c15) * 32 + r4 * 8;

  f32x4 acc[4][4] = {};
  s16x8 bA[4], bB[4];

  // prefetch B for kk=0 (drains at the barrier, ready for loop)
#pragma unroll
  for (int nf = 0; nf < 4; ++nf) bA[nf] = *(const s16x8*)(bp + nf * 512);
  __syncthreads();

  // ---- K-loop: barrier-free, explicit 1-deep B register double-buffer ----
#pragma unroll
  for (int kt = 0; kt < 8; ++kt) {
    const int k0 = 2 * kt, k1 = 2 * kt + 1;
    // issue B(k1) while computing with bA(k0)
#pragma unroll
    for (int nf = 0; nf < 4; ++nf)
      bB[nf] = *(const s16x8*)(bp + k1 * 16384 + nf * 512);
    {
      s16x8 af[4];
      const int ab = a0 + (k0 >> 1) * 128;
#pragma unroll
      for (int mf = 0; mf < 4; ++mf)
        af[mf] = *(const s16x8*)(Ab + ab + mf * 16384);
#pragma unroll
      for (int mf = 0; mf < 4; ++mf)
#pragma unroll
        for (int nf = 0; nf < 4; ++nf)
          acc[mf][nf] = mfma16(af[mf], bA[nf], acc[mf][nf]);
    }
    // issue B(k0+2) while computing with bB(k1)
    if (kt < 7) {
#pragma unroll
      for (int nf = 0; nf < 4; ++nf)
        bA[nf] = *(const s16x8*)(bp + (k0 + 2) * 16384 + nf * 512);
    }
    {
      s16x8 af[4];
      const int ab = a1 + (k1 >> 1) * 128;
#pragma unroll
      for (int mf = 0; mf < 4; ++mf)
        af[mf] = *(const s16x8*)(Ab + ab + mf * 16384);
#pragma unroll
      for (int mf = 0; mf < 4; ++mf)
#pragma unroll
        for (int nf = 0; nf < 4; ++nf)
          acc[mf][nf] = mfma16(af[mf], bB[nf], acc[mf][nf]);
    }
  }

  // ---- epilogue 1: scores[m] = sum_n tanh(acc + z[n]) * V[n] + bv ----
  // C/D layout (16x16x32): col = lane&15, row = (lane>>4)*4 + j   [m89/m91]
#pragma unroll
  for (int mf = 0; mf < 4; ++mf) {
#pragma unroll
    for (int j = 0; j < 4; ++j) {
      float s = 0.f;
#pragma unroll
      for (int nf = 0; nf < 4; ++nf) {
        const int n = wid * 64 + nf * 16 + c15;
        float x = acc[mf][nf][j] + zbuf[n];
        float e = __expf(2.f * x);
        float t = 1.f - 2.f * __builtin_amdgcn_rcpf(e + 1.f);  // tanh(x)
        s += t * vbuf[n];
      }
      s += __shfl_xor(s, 1); s += __shfl_xor(s, 2);
      s += __shfl_xor(s, 4); s += __shfl_xor(s, 8);
      if (c15 == 0) red[wid * BM + mf * 16 + r4 * 4 + j] = s;
    }
  }
  __syncthreads();

  // ---- epilogue 2: wave 0 finishes scores + local softmax stats ----
  if (tid < BM) {
    float s = 0.f;
#pragma unroll
    for (int w = 0; w < 8; ++w) s += red[w * BM + tid];
    s += bv[0];
    scores[m0 + tid] = s;                       // raw score
    float mc = s;
#pragma unroll
    for (int off = 1; off < 64; off <<= 1) mc = fmaxf(mc, __shfl_xor(mc, off));
    float p = __expf(s - mc);
    plds[tid] = p;
    float lc = p;
#pragma unroll
    for (int off = 1; off < 64; off <<= 1) lc += __shfl_xor(lc, off);
    if (tid == 0) { ml[blockIdx.x * 2] = mc; ml[blockIdx.x * 2 + 1] = lc; }
  }
  __syncthreads();

  // ---- epilogue 3: partial ctx[h] = sum_s p[s] * enc_bf16[s][h] (from LDS) --
  {
    const int h = tid;                 // 0..511
    const int q = h >> 3, off = (h & 7) * 2;
    float acc2 = 0.f;
#pragma unroll 8
    for (int r = 0; r < BM; ++r) {
      unsigned short v = *(const unsigned short*)
          ((const char*)Asm + r * 1024 + ((q ^ (r & 7)) * 16) + off);
      acc2 += plds[r] * bf2f(v);
    }
    pctx[(long)blockIdx.x * HDIM + h] = f2bf(acc2);
  }
}

// ---------------- kernel 2: combine partials -> attn (in place) + ctx --------
__global__ void combine(float* __restrict__ attn, const unsigned short* __restrict__ pctx,
                        const float* __restrict__ ml, float* __restrict__ ctx) {
  const int b = blockIdx.x, tid = threadIdx.x;   // 512 threads
  const int lane = tid & 63;
  float m = -1e30f, l = 0.f;
  if (lane < CPB) {
    m = ml[(b * CPB + lane) * 2];
    l = ml[(b * CPB + lane) * 2 + 1];
  }
  float M = m;
#pragma unroll
  for (int off = 1; off < 64; off <<= 1) M = fmaxf(M, __shfl_xor(M, off));
  float le = (lane < CPB) ? l * __expf(m - M) : 0.f;
  float L = le;
#pragma unroll
  for (int off = 1; off < 64; off <<= 1) L += __shfl_xor(L, off);
  const float invL = 1.f / L;

  __shared__ float wc[CPB];
  if (tid < CPB) wc[tid] = __expf(ml[(b * CPB + tid) * 2] - M) * invL;

  // attn rescale in place: attn currently holds raw scores
  float sv[4];
#pragma unroll
  for (int i = 0; i < 4; ++i) sv[i] = attn[(long)b * SEQ + i * 512 + tid];
#pragma unroll
  for (int i = 0; i < 4; ++i)
    attn[(long)b * SEQ + i * 512 + tid] = __expf(sv[i] - M) * invL;

  __syncthreads();
  // ctx[h] = sum_c pctx[c][h] * wc[c]
  float a = 0.f;
#pragma unroll 8
  for (int c = 0; c < CPB; ++c)
    a += bf2f(pctx[(long)(b * CPB + c) * HDIM + tid]) * wc[c];
  ctx[(long)b * HDIM + tid] = a;
}

extern "C" void kernel_launch(void* const* d_in, const int* in_sizes, int n_in,
                              void* d_out, int out_size, void* d_ws, size_t ws_size,
                              hipStream_t stream) {
  const float* enc = (const float*)d_in[0];
  const float* dec = (const float*)d_in[1];
  const float* W1  = (const float*)d_in[2];
  const float* b1  = (const float*)d_in[3];
  const float* W2  = (const float*)d_in[4];
  const float* b2  = (const float*)d_in[5];
  const float* V   = (const float*)d_in[6];
  const float* bv  = (const float*)d_in[7];

  float* out  = (float*)d_out;
  float* ctx  = out;                       // 64*512
  float* attn = out + NB * HDIM;           // 64*2048 (raw scores first, rescaled in place)

  char* ws = (char*)d_ws;
  unsigned short* w1k  = (unsigned short*)ws;                   // 512 KiB (k-step-major)
  float*          zful = (float*)(ws + 524288);                 // 128 KiB
  unsigned short* pctx = (unsigned short*)(ws + 655360);        // 2 MiB  (2048*512 bf16)
  float*          ml   = (float*)(ws + 2752512);                // 16 KiB (2048*2 f32)
  (void)in_sizes; (void)n_in; (void)out_size; (void)ws_size;

  convert_w1<<<128, 256, 0, stream>>>(W1, w1k);
  zproj<<<dim3(NB, 2), 256, 0, stream>>>(dec, W2, b1, b2, zful);
  gemm_fused<<<NBLK, 512, 0, stream>>>(enc, w1k, zful, V, bv, attn, pctx, ml);
  combine<<<NB, 512, 0, stream>>>(attn, pctx, ml, ctx);
}